// Round 11
// baseline (45.977 us; speedup 1.0000x reference)
//
#include <hip/hip_runtime.h>
#include <stdint.h>

#define NS 9

typedef _Float16 f16x8 __attribute__((ext_vector_type(8)));
typedef float    f32x4 __attribute__((ext_vector_type(4)));

#define SBAR __builtin_amdgcn_sched_barrier(0)
#define WAIT_VM(N) do { SBAR; asm volatile("s_waitcnt vmcnt(" #N ")" ::: "memory"); SBAR; } while (0)
#define WAIT_LGKM(N) do { SBAR; asm volatile("s_waitcnt lgkmcnt(" #N ")" ::: "memory"); SBAR; } while (0)

__device__ __forceinline__ unsigned int pk(float a, float b) {
    return __builtin_bit_cast(unsigned int, __builtin_amdgcn_cvt_pkrtz(a, b));
}

// out[b,h,A,C,j] = sum_d q[b,h,A,C,d]*relw[63+j-C,d] + q[b,h,C,A,d]*relh[63+j-C,d]
// v11 = v10's symmetric-pair tiles + 2-bh loop with register prefetch:
// while computing bh0's two passes, bh1's 32 S-loads are in flight (issued
// before the publish barrier). Rel staged once per block, reused for both bh.
// Pass restructured to 4 r-groups x 8 frags with counted lgkmcnt(8) pipelining
// (frag VGPRs 128->64, keeps total <=256 so 2 blocks/CU stay resident).
// All indexing/layout inherited verbatim from v10 (passed, absmax 0.03125).

__global__ __launch_bounds__(256, 2) void relpos_kernel(
    const float* __restrict__ q,
    const float* __restrict__ relh,
    const float* __restrict__ relw,
    float* __restrict__ out)
{
    __shared__ uint4 S1[16][16][8];      // 32 KiB f16: q[Ta0+a][Tc0+cc]
    __shared__ uint4 S2[16][16][8];      // 32 KiB f16: q[Tc0+a][Ta0+cc]
    __shared__ uint4 RL[2][2][32][8];    // 16 KiB f16: [win][tbl][row][chunk]

    const int blk = blockIdx.x;
    const int wid = blk >> 6;            // 0..9 tile pair
    const int m   = blk & 63;            // bh group
    const int bh0 = m << 1, bh1 = bh0 | 1;
    const int ta  = wid < 4 ? 0 : wid < 7 ? 1 : wid < 9 ? 2 : 3;
    const int tc  = wid < 4 ? wid : wid < 7 ? wid - 3 : wid < 9 ? wid - 5 : 3;
    const int Ta0 = ta << 4, Tc0 = tc << 4;

    const int t    = threadIdx.x;
    const int lane = t & 63;
    const int wvu  = __builtin_amdgcn_readfirstlane(t >> 6);
    const int jl   = lane & 15;
    const int k4p  = lane >> 4;

    const int hrow = t >> 7;             // 0/1
    const int u    = t & 127;
    const int cc   = u >> 3;
    const int k4   = u & 7;

    float4 sA[16], sB[16], sR[6];

    auto issueS = [&](int bh_) {
        const float* qs = q + ((size_t)bh_ << 18);
#pragma unroll
        for (int p = 0; p < 8; ++p) {    // S1: q[Ta0+a][Tc0+cc]
            const int a = 2 * p + hrow;
            const float* g1 = qs + (size_t)(Ta0 + a) * 4096 + (size_t)(Tc0 + cc) * 64 + k4 * 8;
            sA[2 * p]     = *(const float4*)g1;
            sA[2 * p + 1] = *(const float4*)(g1 + 4);
        }
        SBAR;
#pragma unroll
        for (int p = 0; p < 8; ++p) {    // S2: q[Tc0+a][Ta0+cc]
            const int a = 2 * p + hrow;
            const float* g2 = qs + (size_t)(Tc0 + a) * 4096 + (size_t)(Ta0 + cc) * 64 + k4 * 8;
            sB[2 * p]     = *(const float4*)g2;
            sB[2 * p + 1] = *(const float4*)(g2 + 4);
        }
        SBAR;
    };
    auto writeS = [&]() {
#pragma unroll
        for (int p = 0; p < 8; ++p) {
            const int a = 2 * p + hrow;
            uint4 w;
            w.x = pk(sA[2 * p].x,     sA[2 * p].y);
            w.y = pk(sA[2 * p].z,     sA[2 * p].w);
            w.z = pk(sA[2 * p + 1].x, sA[2 * p + 1].y);
            w.w = pk(sA[2 * p + 1].z, sA[2 * p + 1].w);
            S1[a][cc][k4 ^ ((a ^ cc) & 7)] = w;
        }
#pragma unroll
        for (int p = 0; p < 8; ++p) {
            const int a = 2 * p + hrow;
            uint4 w;
            w.x = pk(sB[2 * p].x,     sB[2 * p].y);
            w.y = pk(sB[2 * p].z,     sB[2 * p].w);
            w.z = pk(sB[2 * p + 1].x, sB[2 * p + 1].y);
            w.w = pk(sB[2 * p + 1].z, sB[2 * p + 1].w);
            S2[a][cc][k4 ^ ((a ^ cc) & 7)] = w;
        }
    };

    // ---- rel issue (6 loads, oldest) then bh0 S issue (32) ----
#pragma unroll
    for (int mm = 0; mm < 3; ++mm) {
        int ch  = t + (mm << 8);
        int win = ch >= 384;  int r = ch - (win ? 384 : 0);
        int tbl = r >= 192;   r -= (tbl ? 192 : 0);
        const int row = r >> 3, kk = r & 7;
        const int rb0 = win ? (48 - Ta0) : (48 - Tc0);   // rows rb0..rb0+23 <= 71
        const float* rp = (tbl ? relw : relh) + (size_t)(rb0 + row) * 64 + kk * 8;
        sR[2 * mm]     = *(const float4*)rp;
        sR[2 * mm + 1] = *(const float4*)(rp + 4);
    }
    SBAR;
    issueS(bh0);                         // [38 outstanding]

    WAIT_VM(32);                         // rel landed
#pragma unroll
    for (int mm = 0; mm < 3; ++mm) {
        int ch  = t + (mm << 8);
        int win = ch >= 384;  int r = ch - (win ? 384 : 0);
        int tbl = r >= 192;   r -= (tbl ? 192 : 0);
        const int row = r >> 3, kk = r & 7;
        uint4 w;
        w.x = pk(sR[2 * mm].x,     sR[2 * mm].y);
        w.y = pk(sR[2 * mm].z,     sR[2 * mm].w);
        w.z = pk(sR[2 * mm + 1].x, sR[2 * mm + 1].y);
        w.w = pk(sR[2 * mm + 1].z, sR[2 * mm + 1].w);
        RL[win][tbl][row][kk ^ (row & 7)] = w;
    }

    // ---- one pass = one 16x16 output tile; 4 r-groups, counted lgkm ----
    auto pass = [&](const uint4 (*P)[16][8], const uint4 (*Q)[16][8], int w,
                    int Arow0, int Ccol0, size_t ob) {
        uint4 a0[4], b0[4], a1[4], b1[4];
        auto RD = [&](int r, uint4* A, uint4* B) {
            const int kh = (r & 1) << 2;
#pragma unroll
            for (int it = 0; it < 4; ++it) {
                const int cl = (wvu << 2) | it;
                const int sx = (jl ^ cl) & 7;
                A[it] = (r < 2) ? P[jl][cl][(kh + k4p) ^ sx]
                                : Q[cl][jl][(kh + k4p) ^ sx];
                const int rl = (15 - cl) + jl;           // junk rows if jl>=9
                B[it] = RL[w][r < 2 ? 1 : 0][rl][(kh + k4p) ^ (rl & 7)];
            }
        };
        f32x4 acc[4];
#pragma unroll
        for (int it = 0; it < 4; ++it) acc[it] = (f32x4){0.f, 0.f, 0.f, 0.f};
        auto MF = [&](const uint4* A, const uint4* B) {
#pragma unroll
            for (int it = 0; it < 4; ++it)
                acc[it] = __builtin_amdgcn_mfma_f32_16x16x32_f16(
                    __builtin_bit_cast(f16x8, A[it]),
                    __builtin_bit_cast(f16x8, B[it]), acc[it], 0, 0, 0);
        };
        RD(0, a0, b0); RD(1, a1, b1);
        WAIT_LGKM(8);  MF(a0, b0);  RD(2, a0, b0);
        WAIT_LGKM(8);  MF(a1, b1);  RD(3, a1, b1);
        WAIT_LGKM(8);  MF(a0, b0);
        WAIT_LGKM(0);  MF(a1, b1);

        if (jl < NS) {
            const int ar = k4p << 2;
#pragma unroll
            for (int it = 0; it < 4; ++it) {
                const int cl = (wvu << 2) | it;
#pragma unroll
                for (int r = 0; r < 4; ++r)
                    out[((ob + (Arow0 + ar + r)) * 64 + (Ccol0 + cl)) * NS + jl] = acc[it][r];
            }
        }
    };

    // ---- iter 0: bh0 (prefetch bh1 under its compute) ----
    WAIT_VM(0);                          // bh0 S landed
    writeS();
    issueS(bh1);                         // prefetch, 32 outstanding
    WAIT_LGKM(0);
    __builtin_amdgcn_s_barrier();        // publish RL + bh0 tiles
    {
        const size_t ob = (size_t)bh0 << 6;
        pass(S1, S2, 0, Ta0, Tc0, ob);
        if (ta != tc) pass(S2, S1, 1, Tc0, Ta0, ob);
    }
    __builtin_amdgcn_s_barrier();        // all reads of bh0 done

    // ---- iter 1: bh1 ----
    WAIT_VM(0);                          // bh1 S landed (stores drain too)
    writeS();
    WAIT_LGKM(0);
    __builtin_amdgcn_s_barrier();        // publish bh1 tiles
    {
        const size_t ob = (size_t)bh1 << 6;
        pass(S1, S2, 0, Ta0, Tc0, ob);
        if (ta != tc) pass(S2, S1, 1, Tc0, Ta0, ob);
    }
}

extern "C" void kernel_launch(void* const* d_in, const int* in_sizes, int n_in,
                              void* d_out, int out_size, void* d_ws, size_t ws_size,
                              hipStream_t stream) {
    const float* q    = (const float*)d_in[0];
    const float* relh = (const float*)d_in[3];
    const float* relw = (const float*)d_in[4];
    float* out = (float*)d_out;

    // grid: 10 tile pairs x 64 bh-groups (2 bh each)
    relpos_kernel<<<dim3(640), dim3(256), 0, stream>>>(q, relh, relw, out);
}

// Round 12
// 40.264 us; speedup vs baseline: 1.1419x; 1.1419x over previous
//
#include <hip/hip_runtime.h>
#include <stdint.h>

#define NS 9

typedef _Float16 f16x8 __attribute__((ext_vector_type(8)));
typedef float    f32x4 __attribute__((ext_vector_type(4)));

#define SBAR __builtin_amdgcn_sched_barrier(0)
#define WAIT_VM(N) do { SBAR; asm volatile("s_waitcnt vmcnt(" #N ")" ::: "memory"); SBAR; } while (0)
#define WAIT_LGKM(N) do { SBAR; asm volatile("s_waitcnt lgkmcnt(" #N ")" ::: "memory"); SBAR; } while (0)

__device__ __forceinline__ unsigned int pk(float a, float b) {
    return __builtin_bit_cast(unsigned int, __builtin_amdgcn_cvt_pkrtz(a, b));
}

// out[b,h,A,C,j] = sum_d q[b,h,A,C,d]*relw[63+j-C,d] + q[b,h,C,A,d]*relh[63+j-C,d]
// v12 = v10 (37.2us, symmetric-pair 16x16 tiles, grid 1280) with LDS halved to
// 40 KiB via two sequential k-half rounds (d 0..31 / 32..63) -> 4 blocks/CU
// instead of 2. v11's counters showed the family is latency-bound (MfmaUtil 1%,
// VALUBusy 4%, HBM 17%, occ 17%) -> the lever is concurrency, not scheduling.
// Accumulators persist across rounds; stores only at kernel end (v11 lesson:
// vmcnt counts stores). LDS cells stay 128B/8-slot (two a-rows per cell) with
// v10-style XOR swizzle on write+read. Layout/indexing otherwise verbatim v10
// (passed, absmax 0.03125).

__global__ __launch_bounds__(256, 4) void relpos_kernel(
    const float* __restrict__ q,
    const float* __restrict__ relh,
    const float* __restrict__ relw,
    float* __restrict__ out)
{
    __shared__ uint4 S1h[8][16][8];     // 16 KiB: q[Ta0+a][Tc0+cc], one k-half
    __shared__ uint4 S2h[8][16][8];     // 16 KiB: q[Tc0+a][Ta0+cc]
    __shared__ uint4 RLh[2][2][16][8];  //  8 KiB: [win][tbl][row>>1][slot]

    const int blk = blockIdx.x;
    const int bh  = blk & 127;          // b*8+h; same-bh stride 128 -> same XCD
    const int wid = blk >> 7;           // 0..9 tile pair
    const int ta  = wid < 4 ? 0 : wid < 7 ? 1 : wid < 9 ? 2 : 3;
    const int tc  = wid < 4 ? wid : wid < 7 ? wid - 3 : wid < 9 ? wid - 5 : 3;
    const int Ta0 = ta << 4, Tc0 = tc << 4;

    const int t    = threadIdx.x;
    const int lane = t & 63;
    const int wvu  = __builtin_amdgcn_readfirstlane(t >> 6);
    const int jl   = lane & 15;
    const int k4p  = lane >> 4;         // d-chunk 0..3 within the 32-d half

    const float* __restrict__ qs = q + ((size_t)bh << 18);

    // staging coords: thread covers (a = al0+4v, cc = ccs, 32B-pair h8)
    const int al0 = t >> 6;
    const int ccs = (t & 63) >> 2;
    const int h8  = t & 3;

    f32x4 accA[4], accB[4];
#pragma unroll
    for (int i = 0; i < 4; ++i) {
        accA[i] = (f32x4){0.f, 0.f, 0.f, 0.f};
        accB[i] = (f32x4){0.f, 0.f, 0.f, 0.f};
    }

    auto stageRound = [&](int kh) {
        float4 sR[4], sA[8], sB[8];
        // ---- RL issue: 2 chunks/thread x 2 float4 (oldest in vmcnt) ----
#pragma unroll
        for (int m2 = 0; m2 < 2; ++m2) {
            const int ch  = t + (m2 << 8);
            const int win = ch >> 8;
            const int r   = ch & 255;
            const int tbl = r >> 7;
            const int rr  = r & 127;
            const int row = rr >> 2, kk = rr & 3;
            const int rb0 = win ? (48 - Ta0) : (48 - Tc0);
            int gr = rb0 + row; if (gr > 71) gr = 71;   // junk rows, never stored
            const float* rp = (tbl ? relw : relh) + (size_t)gr * 64 + kh * 32 + kk * 8;
            sR[2 * m2]     = *(const float4*)rp;
            sR[2 * m2 + 1] = *(const float4*)(rp + 4);
        }
        SBAR;
        // ---- S1 issue: 8 loads ----
#pragma unroll
        for (int v = 0; v < 4; ++v) {
            const int a = al0 + (v << 2);
            const float* p1 = qs + (size_t)(Ta0 + a) * 4096 + (size_t)(Tc0 + ccs) * 64
                                 + kh * 32 + h8 * 8;
            sA[2 * v]     = *(const float4*)p1;
            sA[2 * v + 1] = *(const float4*)(p1 + 4);
        }
        SBAR;
        // ---- S2 issue: 8 loads ----
#pragma unroll
        for (int v = 0; v < 4; ++v) {
            const int a = al0 + (v << 2);
            const float* p2 = qs + (size_t)(Tc0 + a) * 4096 + (size_t)(Ta0 + ccs) * 64
                                 + kh * 32 + h8 * 8;
            sB[2 * v]     = *(const float4*)p2;
            sB[2 * v + 1] = *(const float4*)(p2 + 4);
        }
        SBAR;

        WAIT_VM(16);                    // RL landed
#pragma unroll
        for (int m2 = 0; m2 < 2; ++m2) {
            const int ch  = t + (m2 << 8);
            const int win = ch >> 8;
            const int r   = ch & 255;
            const int tbl = r >> 7;
            const int rr  = r & 127;
            const int row = rr >> 2, kk = rr & 3;
            uint4 w;
            w.x = pk(sR[2 * m2].x,     sR[2 * m2].y);
            w.y = pk(sR[2 * m2].z,     sR[2 * m2].w);
            w.z = pk(sR[2 * m2 + 1].x, sR[2 * m2 + 1].y);
            w.w = pk(sR[2 * m2 + 1].z, sR[2 * m2 + 1].w);
            RLh[win][tbl][row >> 1][(((row & 1) << 2) | kk) ^ ((row >> 1) & 7)] = w;
        }
        WAIT_VM(8);                     // S1 landed
#pragma unroll
        for (int v = 0; v < 4; ++v) {
            const int a = al0 + (v << 2);
            uint4 w;
            w.x = pk(sA[2 * v].x,     sA[2 * v].y);
            w.y = pk(sA[2 * v].z,     sA[2 * v].w);
            w.z = pk(sA[2 * v + 1].x, sA[2 * v + 1].y);
            w.w = pk(sA[2 * v + 1].z, sA[2 * v + 1].w);
            S1h[a >> 1][ccs][((((a & 1) << 2) | h8) ^ ((a >> 1) & 7) ^ (ccs & 7))] = w;
        }
        WAIT_VM(0);                     // S2 landed
#pragma unroll
        for (int v = 0; v < 4; ++v) {
            const int a = al0 + (v << 2);
            uint4 w;
            w.x = pk(sB[2 * v].x,     sB[2 * v].y);
            w.y = pk(sB[2 * v].z,     sB[2 * v].w);
            w.z = pk(sB[2 * v + 1].x, sB[2 * v + 1].y);
            w.w = pk(sB[2 * v + 1].z, sB[2 * v + 1].w);
            S2h[a >> 1][ccs][((((a & 1) << 2) | h8) ^ ((a >> 1) & 7) ^ (ccs & 7))] = w;
        }
    };

    auto passCompute = [&](const uint4 (*P)[16][8], const uint4 (*Q)[16][8],
                           int win, f32x4 (&acc)[4]) {
        uint4 A0[4], B0[4], A1[4], B1[4];
        auto RD2 = [&](int itb, uint4* A, uint4* B) {
#pragma unroll
            for (int s = 0; s < 2; ++s) {
                const int it = itb + s;
                const int cl = (wvu << 2) | it;
                A[2 * s]     = P[jl >> 1][cl][((((jl & 1) << 2) | k4p) ^ ((jl >> 1) & 7) ^ (cl & 7))];
                A[2 * s + 1] = Q[cl >> 1][jl][((((cl & 1) << 2) | k4p) ^ ((cl >> 1) & 7) ^ (jl & 7))];
                const int rl = (15 - cl) + jl;        // 0..30; junk if jl>=9
                const int sl = (((rl & 1) << 2) | k4p) ^ ((rl >> 1) & 7);
                B[2 * s]     = RLh[win][1][rl >> 1][sl];   // relw
                B[2 * s + 1] = RLh[win][0][rl >> 1][sl];   // relh
            }
        };
        auto MF2 = [&](int itb, const uint4* A, const uint4* B) {
#pragma unroll
            for (int s = 0; s < 2; ++s) {
                const int it = itb + s;
                acc[it] = __builtin_amdgcn_mfma_f32_16x16x32_f16(
                    __builtin_bit_cast(f16x8, A[2 * s]),
                    __builtin_bit_cast(f16x8, B[2 * s]), acc[it], 0, 0, 0);
                acc[it] = __builtin_amdgcn_mfma_f32_16x16x32_f16(
                    __builtin_bit_cast(f16x8, A[2 * s + 1]),
                    __builtin_bit_cast(f16x8, B[2 * s + 1]), acc[it], 0, 0, 0);
            }
        };
        RD2(0, A0, B0); RD2(2, A1, B1);
        WAIT_LGKM(8); MF2(0, A0, B0);
        WAIT_LGKM(0); MF2(2, A1, B1);
    };

    // ---- round 0 (d 0..31) ----
    stageRound(0);
    WAIT_LGKM(0);
    __builtin_amdgcn_s_barrier();       // publish
    passCompute(S1h, S2h, 0, accA);
    if (ta != tc) passCompute(S2h, S1h, 1, accB);
    __builtin_amdgcn_s_barrier();       // WAR: all reads done before overwrite

    // ---- round 1 (d 32..63) ----
    stageRound(1);
    WAIT_LGKM(0);
    __builtin_amdgcn_s_barrier();       // publish
    passCompute(S1h, S2h, 0, accA);
    if (ta != tc) passCompute(S2h, S1h, 1, accB);

    // ---- stores: col j=lane&15 (<9), row a=(lane>>4)*4+reg ----
    if (jl < NS) {
        const int ar = k4p << 2;
        const size_t ob = (size_t)bh << 6;
#pragma unroll
        for (int it = 0; it < 4; ++it) {
            const int cl = (wvu << 2) | it;
#pragma unroll
            for (int r = 0; r < 4; ++r)
                out[((ob + (Ta0 + ar + r)) * 64 + (Tc0 + cl)) * NS + jl] = accA[it][r];
        }
        if (ta != tc) {
#pragma unroll
            for (int it = 0; it < 4; ++it) {
                const int cl = (wvu << 2) | it;
#pragma unroll
                for (int r = 0; r < 4; ++r)
                    out[((ob + (Tc0 + ar + r)) * 64 + (Ta0 + cl)) * NS + jl] = accB[it][r];
            }
        }
    }
}

extern "C" void kernel_launch(void* const* d_in, const int* in_sizes, int n_in,
                              void* d_out, int out_size, void* d_ws, size_t ws_size,
                              hipStream_t stream) {
    const float* q    = (const float*)d_in[0];
    const float* relh = (const float*)d_in[3];
    const float* relw = (const float*)d_in[4];
    float* out = (float*)d_out;

    // grid: 10 tile pairs x 128 bh
    relpos_kernel<<<dim3(1280), dim3(256), 0, stream>>>(q, relh, relw, out);
}

// Round 13
// 31.188 us; speedup vs baseline: 1.4742x; 1.2910x over previous
//
#include <hip/hip_runtime.h>
#include <stdint.h>

#define NS 9

typedef _Float16 f16x8 __attribute__((ext_vector_type(8)));
typedef float    f32x4 __attribute__((ext_vector_type(4)));

#define SBAR __builtin_amdgcn_sched_barrier(0)
#define WAIT_VM(N) do { SBAR; asm volatile("s_waitcnt vmcnt(" #N ")" ::: "memory"); SBAR; } while (0)
#define WAIT_LGKM(N) do { SBAR; asm volatile("s_waitcnt lgkmcnt(" #N ")" ::: "memory"); SBAR; } while (0)

__device__ __forceinline__ unsigned int pk(float a, float b) {
    return __builtin_bit_cast(unsigned int, __builtin_amdgcn_cvt_pkrtz(a, b));
}

// out[b,h,A,C,j] = sum_d q[b,h,A,C,d]*relw[63+j-C,d] + q[b,h,C,A,d]*relh[63+j-C,d]
// v13 = v10 (37.2us champion) widened to 512-thread blocks: same tile-pair
// per block, same 80KiB LDS, same single stage->drain cycle, but waves 0-3
// compute pass1 while waves 4-7 compute pass2 concurrently -> 2 blocks/CU now
// = 16 waves/CU (4/SIMD) instead of 8 (2/SIMD). v11/v12 counters showed pure
// latency-bound (all pipes <5%, occ 17%): the lever is TLP with no extra
// serial drains. Staging remapped: thread t, iter i loads float4 F=i*512+t
// (consecutive threads = consecutive 16B, fully coalesced) and writes one
// uint2 f16 (ds_write_b64) -- no cross-float4 pairing needed. All swizzle /
// fragment formulas bit-identical to v10 (passed, absmax 0.03125).

__global__ __launch_bounds__(512, 4) void relpos_kernel(
    const float* __restrict__ q,
    const float* __restrict__ relh,
    const float* __restrict__ relw,
    float* __restrict__ out)
{
    __shared__ uint4 S1[16][16][8];      // 32 KiB f16: q[Ta0+a][Tc0+cc]
    __shared__ uint4 S2[16][16][8];      // 32 KiB f16: q[Tc0+a][Ta0+cc]
    __shared__ uint4 RL[2][2][32][8];    // 16 KiB f16: [win][tbl][row][slot]

    const int blk = blockIdx.x;
    const int bh  = blk & 127;           // b*8+h; stride 128 -> same XCD
    const int wid = blk >> 7;            // 0..9 tile pair
    const int ta  = wid < 4 ? 0 : wid < 7 ? 1 : wid < 9 ? 2 : 3;
    const int tc  = wid < 4 ? wid : wid < 7 ? wid - 3 : wid < 9 ? wid - 5 : 3;
    const int Ta0 = ta << 4, Tc0 = tc << 4;

    const int t    = threadIdx.x;        // 0..511
    const int lane = t & 63;
    const int wvu  = __builtin_amdgcn_readfirstlane(t >> 6);   // 0..7
    const int wg   = wvu >> 2;           // 0: pass1 tile, 1: pass2 twin tile
    const int wl   = wvu & 3;            // column-group within pass
    const int jl   = lane & 15;
    const int k4p  = lane >> 4;

    const float* __restrict__ qs = q + ((size_t)bh << 18);

    // ---- issue: S1 (8), S2 (8), RL (3) -- all coalesced ----
    float4 sA[8], sB[8], sR[3];
#pragma unroll
    for (int i = 0; i < 8; ++i) {        // S1 float4 F = i*512 + t
        const int F  = (i << 9) + t;
        const int al = F >> 8, cc = (F >> 4) & 15, g = F & 15;
        sA[i] = *(const float4*)(qs + (size_t)(Ta0 + al) * 4096
                                    + (size_t)(Tc0 + cc) * 64 + (g << 2));
    }
    SBAR;
#pragma unroll
    for (int i = 0; i < 8; ++i) {        // S2
        const int F  = (i << 9) + t;
        const int al = F >> 8, cc = (F >> 4) & 15, g = F & 15;
        sB[i] = *(const float4*)(qs + (size_t)(Tc0 + al) * 4096
                                    + (size_t)(Ta0 + cc) * 64 + (g << 2));
    }
    SBAR;
#pragma unroll
    for (int m = 0; m < 3; ++m) {        // RL: 1536 float4 = 2win x 2tbl x 24row x 16
        const int F   = (m << 9) + t;
        const int win = F >= 768;
        const int r   = F - (win ? 768 : 0);
        const int tbl = r >= 384;
        const int rr  = r - (tbl ? 384 : 0);
        const int row = rr >> 4, g = rr & 15;
        const int rb0 = win ? (48 - Ta0) : (48 - Tc0);
        int gr = rb0 + row; if (gr > 71) gr = 71;
        sR[m] = *(const float4*)((tbl ? relw : relh) + (size_t)gr * 64 + (g << 2));
    }
    SBAR;

    // ---- drains + cvt + ds_write_b64 ----
    WAIT_VM(11);                         // S1 landed
#pragma unroll
    for (int i = 0; i < 8; ++i) {
        const int F  = (i << 9) + t;
        const int al = F >> 8, cc = (F >> 4) & 15, g = F & 15;
        const int slot = (g >> 1) ^ ((al ^ cc) & 7), half = g & 1;
        uint2 w; w.x = pk(sA[i].x, sA[i].y); w.y = pk(sA[i].z, sA[i].w);
        ((uint2*)&S1[al][cc][slot])[half] = w;
    }
    WAIT_VM(3);                          // S2 landed
#pragma unroll
    for (int i = 0; i < 8; ++i) {
        const int F  = (i << 9) + t;
        const int al = F >> 8, cc = (F >> 4) & 15, g = F & 15;
        const int slot = (g >> 1) ^ ((al ^ cc) & 7), half = g & 1;
        uint2 w; w.x = pk(sB[i].x, sB[i].y); w.y = pk(sB[i].z, sB[i].w);
        ((uint2*)&S2[al][cc][slot])[half] = w;
    }
    WAIT_VM(0);                          // RL landed
#pragma unroll
    for (int m = 0; m < 3; ++m) {
        const int F   = (m << 9) + t;
        const int win = F >= 768;
        const int r   = F - (win ? 768 : 0);
        const int tbl = r >= 384;
        const int rr  = r - (tbl ? 384 : 0);
        const int row = rr >> 4, g = rr & 15;
        const int slot = (g >> 1) ^ (row & 7), half = g & 1;
        uint2 w; w.x = pk(sR[m].x, sR[m].y); w.y = pk(sR[m].z, sR[m].w);
        ((uint2*)&RL[win][tbl][row][slot])[half] = w;
    }
    WAIT_LGKM(0);
    __builtin_amdgcn_s_barrier();        // publish LDS

    // ---- pass: waves 0-3 tile (ta,tc); waves 4-7 twin (tc,ta) ----
    if (wg == 0 || ta != tc) {
        const uint4 (*P)[16][8] = wg ? S2 : S1;
        const uint4 (*Q)[16][8] = wg ? S1 : S2;
        const int win   = wg;
        const int Arow0 = wg ? Tc0 : Ta0;
        const int Ccol0 = wg ? Ta0 : Tc0;

        uint4 A0[4], B0[4], A1[4], B1[4];
        auto RD = [&](int r, uint4* A, uint4* B) {
            const int kh = (r & 1) << 2;
#pragma unroll
            for (int it = 0; it < 4; ++it) {
                const int cl = (wl << 2) | it;
                const int sx = (jl ^ cl) & 7;
                A[it] = (r < 2) ? P[jl][cl][(kh + k4p) ^ sx]
                                : Q[cl][jl][(kh + k4p) ^ sx];
                const int rl = (15 - cl) + jl;        // junk rows if jl>=9
                B[it] = RL[win][r < 2 ? 1 : 0][rl][(kh + k4p) ^ (rl & 7)];
            }
        };
        f32x4 acc[4];
#pragma unroll
        for (int it = 0; it < 4; ++it) acc[it] = (f32x4){0.f, 0.f, 0.f, 0.f};
        auto MF = [&](const uint4* A, const uint4* B) {
#pragma unroll
            for (int it = 0; it < 4; ++it)
                acc[it] = __builtin_amdgcn_mfma_f32_16x16x32_f16(
                    __builtin_bit_cast(f16x8, A[it]),
                    __builtin_bit_cast(f16x8, B[it]), acc[it], 0, 0, 0);
        };
        RD(0, A0, B0); RD(1, A1, B1);
        WAIT_LGKM(8);  MF(A0, B0);  RD(2, A0, B0);
        WAIT_LGKM(8);  MF(A1, B1);  RD(3, A1, B1);
        WAIT_LGKM(8);  MF(A0, B0);
        WAIT_LGKM(0);  MF(A1, B1);

        if (jl < NS) {
            const int ar = k4p << 2;
            const size_t ob = (size_t)bh << 6;
#pragma unroll
            for (int it = 0; it < 4; ++it) {
                const int cl = (wl << 2) | it;
#pragma unroll
                for (int r = 0; r < 4; ++r)
                    out[((ob + (Arow0 + ar + r)) * 64 + (Ccol0 + cl)) * NS + jl] = acc[it][r];
            }
        }
    }
}

extern "C" void kernel_launch(void* const* d_in, const int* in_sizes, int n_in,
                              void* d_out, int out_size, void* d_ws, size_t ws_size,
                              hipStream_t stream) {
    const float* q    = (const float*)d_in[0];
    const float* relh = (const float*)d_in[3];
    const float* relw = (const float*)d_in[4];
    float* out = (float*)d_out;

    // grid: 10 tile pairs x 128 bh; 512-thread blocks
    relpos_kernel<<<dim3(1280), dim3(512), 0, stream>>>(q, relh, relw, out);
}